// Round 20
// baseline (53.592 us; speedup 1.0000x reference)
//
#include <hip/hip_runtime.h>
#include <hip/hip_bf16.h>

#define B_ 8
#define C_ 96
#define H_ 64
#define W_ 96
#define DD 21
#define RAWS 49            // prep LDS row stride (uints): conflict-free gather
#define LDR 99             // Dst row stride (floats): 99 % 32 = 3 (odd) ->
                           // extract bank = 3*lr - 4*lg + C: 16 banks, ~2-way

typedef __attribute__((ext_vector_type(8))) short sh8;
typedef __attribute__((ext_vector_type(4))) float fx4;

// Fragment-major bf16 tensors: innermost [lane(64)][e(8)] = 1KB per k-block.
// d1F: [b][y][p][ut(3)][k(3)][lane][8]
// d2F: [b][yi(64)][p][wt(5)][k(3)][lane][8] -- INTERIOR ROWS ONLY (yi=yp-20).
// Border rows never materialized; corr zero-fills registers (R17: -2.3us).
__device__ __attribute__((aligned(16))) unsigned short g_d1F[B_*H_*2*3*3*512];
__device__ __attribute__((aligned(16))) unsigned short g_d2F[(size_t)B_*64*2*5*3*512];

// Fused prep kernel, XCD-ALIGNED 1D grid (R14: -4.1us): gid = b + 8*t, so
// batch b's producers run on XCD b = the XCD whose corr blocks consume them.
//  t in [0,64):    d1 row y=t    -> g_d1F
//  t in [64,128):  d2 row y=t-64 -> g_d2F (compact interior row index)
__global__ __launch_bounds__(256) void prep_all(const float* __restrict__ d1,
                                                const float* __restrict__ d2) {
  __shared__ unsigned int raw[C_*RAWS];    // [c][w] packed (p0 | p1<<16)
  const int b = blockIdx.x & 7;
  const int t = blockIdx.x >> 3;

  if (t >= 64) {
    const int y = t - 64;
    unsigned short* ob = g_d2F + (size_t)(b*64 + y)*(2*15*512);
    for (int idx = threadIdx.x; idx < C_*48; idx += 256) {
      int c = idx / 48, w = idx % 48;
      const float2 v = *(const float2*)(d2 + (((b*C_ + c)*H_ + y)*W_ + 2*w));
      __hip_bfloat16 h0 = __float2bfloat16(v.x), h1 = __float2bfloat16(v.y);
      raw[c*RAWS + w] = (unsigned)*(unsigned short*)&h0 |
                        ((unsigned)*(unsigned short*)&h1 << 16);
    }
    __syncthreads();
    for (int s = threadIdx.x; s < 2*15*64; s += 256) {
      int lane = s & 63, q = s >> 6;
      int kk = q % 3, wt = (q/3) % 5, p = q / 15;
      int w = wt*16 + (lane & 15) - 10;    // x-pad: stored col = w' - 10
      int cb = kk*32 + (lane >> 4)*8;
      uint4 o; o.x = o.y = o.z = o.w = 0u;
      if (w >= 0 && w < 48) {
        unsigned short tmp[8];
        #pragma unroll
        for (int e = 0; e < 8; ++e) {
          unsigned pk = raw[(cb + e)*RAWS + w];
          tmp[e] = (unsigned short)(p ? (pk >> 16) : pk);
        }
        o = *(const uint4*)tmp;
      }
      *(uint4*)(ob + (size_t)s*8) = o;
    }
  } else {
    const int y = t;
    for (int idx = threadIdx.x; idx < C_*48; idx += 256) {
      int c = idx / 48, w = idx % 48;
      const float2 v = *(const float2*)(d1 + (((b*C_ + c)*H_ + y)*W_ + 2*w));
      __hip_bfloat16 h0 = __float2bfloat16(v.x), h1 = __float2bfloat16(v.y);
      raw[c*RAWS + w] = (unsigned)*(unsigned short*)&h0 |
                        ((unsigned)*(unsigned short*)&h1 << 16);
    }
    __syncthreads();
    unsigned short* ob = g_d1F + (size_t)(b*H_ + y)*(2*9*512);
    for (int s = threadIdx.x; s < 2*9*64; s += 256) {
      int lane = s & 63, q = s >> 6;
      int kk = q % 3, ut = (q/3) % 3, p = q / 9;
      int w = ut*16 + (lane & 15);
      int cb = kk*32 + (lane >> 4)*8;
      unsigned short tmp[8];
      #pragma unroll
      for (int e = 0; e < 8; ++e) {
        unsigned pk = raw[(cb + e)*RAWS + w];
        tmp[e] = (unsigned short)(p ? (pk >> 16) : pk);
      }
      *(uint4*)(ob + (size_t)s*8) = *(const uint4*)tmp;
    }
  }
}

// One block per (b, y4-group, i): 128 threads = 2 waves (p=0,1), 12 substeps
// (yl 0..3 x mt 0..2), champion-identical MFMA/extract math. This round's
// single variable vs R16: Dst row R = yl*21 + j with ODD stride 99 -- the
// extract's per-lane j sits on a stride-1 row step so bank = 3*lr - 4*lg + C
// sweeps 16 banks (R16's R=4j+yl made every step 4-aligned -> >=8-way,
// 12M conflicts). Store: each of the 21 planes leaves as a 1536B CONTIGUOUS
// NT run (4 consecutive y x 96 x), 12x the champion's 128B granularity.
// Single-buffered Dst, ONE __syncthreads -- minimal race surface.
// G=A.B^T band: out[b, i*21+j, y, 2u+p] = G_p[u, u+j], j in [0,21).
__global__ __launch_bounds__(128, 4) void corr_main(const float* __restrict__ s1,
                                                    const float* __restrict__ s2,
                                                    const float* __restrict__ os,
                                                    float* __restrict__ out) {
  __shared__ float Dst[84*LDR];            // 33264 B -> 4 blocks/CU
  const int gid = blockIdx.x;
  const int b = gid & 7;                   // XCD affinity (matches prep)
  int t = gid >> 3;
  const int yq = t & 15;                   // y0 = yq*4
  const int i  = t >> 4;                   // [0,21)
  const int y0 = yq*4;
  const int p = threadIdx.x >> 6;
  const int lane = threadIdx.x & 63;
  const int lr = lane & 15, lg = lane >> 4;
  const float scale = s1[0]*s2[0] / (96.0f * os[0]);

  #pragma unroll
  for (int yl = 0; yl < 4; ++yl) {
    const int y = y0 + yl;
    const int row = y + 2*i;               // [0,104); interior = [20,84)
    const bool rv = (row >= 20) & (row < 84);
    const unsigned short* aRow =
        g_d1F + (size_t)((b*H_ + y)*2 + p)*(9*512) + lane*8;
    const unsigned short* bRow =
        g_d2F + (size_t)((b*64 + (rv ? row - 20 : 0))*2 + p)*(15*512) + lane*8;

    #pragma unroll
    for (int mt = 0; mt < 3; ++mt) {
      sh8 aF[3], bF[9];
      #pragma unroll
      for (int k = 0; k < 3; ++k)
        aF[k] = *(const sh8*)(aRow + (mt*3 + k)*512);
      if (rv) {
        #pragma unroll
        for (int n = 0; n < 3; ++n)
          #pragma unroll
          for (int k = 0; k < 3; ++k)
            bF[k*3+n] = *(const sh8*)(bRow + ((mt + n)*3 + k)*512);
      } else {
        #pragma unroll
        for (int q = 0; q < 9; ++q)
          bF[q] = (sh8){0,0,0,0,0,0,0,0};
      }

      fx4 acc[3] = {fx4{0,0,0,0}, fx4{0,0,0,0}, fx4{0,0,0,0}};
      #pragma unroll
      for (int k = 0; k < 3; ++k)
        #pragma unroll
        for (int n = 0; n < 3; ++n)
          acc[n] = __builtin_amdgcn_mfma_f32_16x16x32_bf16(aF[k], bF[k*3+n],
                                                           acc[n], 0, 0, 0);

      // band extract: col w'=16(mt+n)+lr, row u=16mt+4lg+r ; j=w'-u
      // x = 2u+p ; Dst row R = yl*21+j (stride-1 in j -> odd-stride banks)
      #pragma unroll
      for (int n = 0; n < 3; ++n)
        #pragma unroll
        for (int r = 0; r < 4; ++r) {
          int j = 16*n + lr - 4*lg - r;
          if (j >= 0 && j < DD) {
            int x = 2*(16*mt + 4*lg + r) + p;
            Dst[(yl*21 + j)*LDR + x] = acc[n][r];
          }
        }
    }
  }
  __syncthreads();

  // store: 21 planes x (4y x 96x) = 1536B contiguous NT per plane
  const size_t obase = ((size_t)(b*441 + i*DD)*H_ + y0)*W_;
  for (int q = threadIdx.x; q < DD*96; q += 128) {   // 2016 fx4
    int j = q / 96, rem = q % 96;
    int yy = rem / 24, x4 = (rem % 24)*4;
    const float* rp = &Dst[(yy*21 + j)*LDR + x4];
    fx4 v; v[0] = rp[0]; v[1] = rp[1]; v[2] = rp[2]; v[3] = rp[3];
    v = v * scale;
    __builtin_nontemporal_store(
        v, (fx4*)(out + obase + (size_t)j*(H_*W_) + yy*W_ + x4));
  }
}

extern "C" void kernel_launch(void* const* d_in, const int* in_sizes, int n_in,
                              void* d_out, int out_size, void* d_ws, size_t ws_size,
                              hipStream_t stream) {
  const float* d1 = (const float*)d_in[0];
  const float* d2 = (const float*)d_in[1];
  const float* s1 = (const float*)d_in[2];
  const float* s2 = (const float*)d_in[3];
  const float* os = (const float*)d_in[5];   // inter_scale (d_in[4]) unused

  prep_all<<<128*B_, 256, 0, stream>>>(d1, d2);
  corr_main<<<B_*16*DD, 128, 0, stream>>>(s1, s2, os, (float*)d_out);
}

// Round 21
// 39.343 us; speedup vs baseline: 1.3622x; 1.3622x over previous
//
#include <hip/hip_runtime.h>
#include <hip/hip_bf16.h>

#define B_ 8
#define C_ 96
#define H_ 64
#define W_ 96
#define DD 21
#define NI 7               // i-values per block (per y of the pair)
#define ISPLIT 3           // 21 / NI
#define LDSTm 37           // Dst row stride (floats): odd -> 5j sweeps 16 banks
#define RAWS 49            // prep LDS row stride (uints): conflict-free gather

typedef __attribute__((ext_vector_type(8))) short sh8;
typedef __attribute__((ext_vector_type(4))) float fx4;

// Fragment-major bf16 tensors: innermost [lane(64)][e(8)] = 1KB per k-block,
// so a wave's MFMA operand load is base + lane*16B (fully coalesced).
// d1F: [b][y][p][ut(3)][k(3)][lane][8]
// d2F: [b][yi(64)][p][wt(5)][k(3)][lane][8] -- INTERIOR ROWS ONLY (yi=yp-20).
// Border rows never materialized; corr zero-fills registers instead.
// Per-XCD working set d1F[b]+d2F[b] = 3.1 MB < 4 MB L2 (R17: -2.3us).
__device__ __attribute__((aligned(16))) unsigned short g_d1F[B_*H_*2*3*3*512];
__device__ __attribute__((aligned(16))) unsigned short g_d2F[(size_t)B_*64*2*5*3*512];

// Fused prep kernel, XCD-ALIGNED 1D grid (R14: -4.1us): gid = b + 8*t, so
// batch b's producers run on XCD b = the XCD whose corr blocks consume them.
//  t in [0,64):    d1 row y=t    -> g_d1F
//  t in [64,128):  d2 row y=t-64 -> g_d2F (compact interior row index)
__global__ __launch_bounds__(256) void prep_all(const float* __restrict__ d1,
                                                const float* __restrict__ d2) {
  __shared__ unsigned int raw[C_*RAWS];    // [c][w] packed (p0 | p1<<16)
  const int b = blockIdx.x & 7;
  const int t = blockIdx.x >> 3;

  if (t >= 64) {
    const int y = t - 64;
    unsigned short* ob = g_d2F + (size_t)(b*64 + y)*(2*15*512);
    for (int idx = threadIdx.x; idx < C_*48; idx += 256) {
      int c = idx / 48, w = idx % 48;
      const float2 v = *(const float2*)(d2 + (((b*C_ + c)*H_ + y)*W_ + 2*w));
      __hip_bfloat16 h0 = __float2bfloat16(v.x), h1 = __float2bfloat16(v.y);
      raw[c*RAWS + w] = (unsigned)*(unsigned short*)&h0 |
                        ((unsigned)*(unsigned short*)&h1 << 16);
    }
    __syncthreads();
    for (int s = threadIdx.x; s < 2*15*64; s += 256) {
      int lane = s & 63, q = s >> 6;
      int kk = q % 3, wt = (q/3) % 5, p = q / 15;
      int w = wt*16 + (lane & 15) - 10;    // x-pad: stored col = w' - 10
      int cb = kk*32 + (lane >> 4)*8;
      uint4 o; o.x = o.y = o.z = o.w = 0u;
      if (w >= 0 && w < 48) {
        unsigned short tmp[8];
        #pragma unroll
        for (int e = 0; e < 8; ++e) {
          unsigned pk = raw[(cb + e)*RAWS + w];
          tmp[e] = (unsigned short)(p ? (pk >> 16) : pk);
        }
        o = *(const uint4*)tmp;
      }
      *(uint4*)(ob + (size_t)s*8) = o;
    }
  } else {
    const int y = t;
    for (int idx = threadIdx.x; idx < C_*48; idx += 256) {
      int c = idx / 48, w = idx % 48;
      const float2 v = *(const float2*)(d1 + (((b*C_ + c)*H_ + y)*W_ + 2*w));
      __hip_bfloat16 h0 = __float2bfloat16(v.x), h1 = __float2bfloat16(v.y);
      raw[c*RAWS + w] = (unsigned)*(unsigned short*)&h0 |
                        ((unsigned)*(unsigned short*)&h1 << 16);
    }
    __syncthreads();
    unsigned short* ob = g_d1F + (size_t)(b*H_ + y)*(2*9*512);
    for (int s = threadIdx.x; s < 2*9*64; s += 256) {
      int lane = s & 63, q = s >> 6;
      int kk = q % 3, ut = (q/3) % 3, p = q / 9;
      int w = ut*16 + (lane & 15);
      int cb = kk*32 + (lane >> 4)*8;
      unsigned short tmp[8];
      #pragma unroll
      for (int e = 0; e < 8; ++e) {
        unsigned pk = raw[(cb + e)*RAWS + w];
        tmp[e] = (unsigned short)(p ? (pk >> 16) : pk);
      }
      *(uint4*)(ob + (size_t)s*8) = *(const uint4*)tmp;
    }
  }
}

// LOADB with wave-uniform border handling (R17): interior rows load from the
// compact d2F; border rows ZERO the registers (MFMA-on-zeros = correct zero
// outputs). Named register array, compile-time indices (rule #20).
#define LOADB(BF, ROW) do {                                                    \
    const int row_ = (ROW);                                                    \
    if (row_ >= 20 && row_ < 84) {                                             \
      const unsigned short* rb_ =                                              \
          g_d2F + (size_t)(((b*64 + (row_ - 20))*2 + p)*5 + mt)*(3*512)        \
          + lane*8;                                                            \
      _Pragma("unroll")                                                        \
      for (int n_ = 0; n_ < 3; ++n_)                                           \
        _Pragma("unroll")                                                      \
        for (int k_ = 0; k_ < 3; ++k_)                                         \
          BF[k_*3+n_] = *(const sh8*)(rb_ + (n_*3 + k_)*512);                  \
    } else {                                                                   \
      _Pragma("unroll")                                                        \
      for (int t_ = 0; t_ < 9; ++t_)                                           \
        BF[t_] = (sh8){0,0,0,0,0,0,0,0};                                       \
    }                                                                          \
  } while (0)

// HARDENED sync (R18 post-mortem): full __syncthreads() (vmcnt+lgkm drain,
// no inline-asm reordering hazards) + 3-buffer Dst rotation, so an extract
// into a buffer is >=3 full barriers after the last store-read of that
// buffer. NT packed-fx4 stores (R10/R15).
#define COMBO(AF, Y, I, BUF) do {                                              \
    fx4 acc[3] = {fx4{0,0,0,0}, fx4{0,0,0,0}, fx4{0,0,0,0}};                   \
    _Pragma("unroll")                                                          \
    for (int k_ = 0; k_ < 3; ++k_)                                             \
      _Pragma("unroll")                                                        \
      for (int n_ = 0; n_ < 3; ++n_)                                           \
        acc[n_] = __builtin_amdgcn_mfma_f32_16x16x32_bf16(AF[k_], bF[k_*3+n_], \
                                                          acc[n_], 0, 0, 0);   \
    _Pragma("unroll")                                                          \
    for (int n_ = 0; n_ < 3; ++n_)                                             \
      _Pragma("unroll")                                                        \
      for (int r_ = 0; r_ < 4; ++r_) {                                         \
        int j_ = 16*n_ + lr - 4*lg - r_;                                       \
        if (j_ >= 0 && j_ < DD)                                                \
          Dst[BUF][j_*LDSTm + 2*(4*lg + r_) + p] = acc[n_][r_];                \
      }                                                                        \
    __syncthreads();                                                           \
    size_t obase = (size_t)((b*441 + (I)*DD)*H_ + (Y))*W_ + 2*m0;              \
    for (int q_ = threadIdx.x; q_ < DD*8; q_ += 128) {                         \
      int j_ = q_ >> 3, xi_ = q_ & 7;                                          \
      const float* rp_ = &Dst[BUF][j_*LDSTm + xi_*4];                          \
      fx4 v_; v_[0] = rp_[0]; v_[1] = rp_[1]; v_[2] = rp_[2]; v_[3] = rp_[3];  \
      v_ = v_ * scale;                                                         \
      __builtin_nontemporal_store(                                             \
          v_, (fx4*)(out + obase + (size_t)j_*(H_*W_) + xi_*4));               \
    }                                                                          \
  } while (0)

// One block per (b, mt, y-pair, i-seg): 128 threads = 2 waves (p=0,1).
// y-pair = {y0, y0+2}: output (y,i) uses B row y+2i, so rows for (y0,i) and
// (y0+2,i-1) COINCIDE -> 8 LOADBs serve 14 combos (L2 reads 580->~300 MB).
// G=A.B^T band: out[b, i*21+j, y, 2u+p] = G_p[u, u+j], j in [0,21).
__global__ __launch_bounds__(128, 4) void corr_main(const float* __restrict__ s1,
                                                    const float* __restrict__ s2,
                                                    const float* __restrict__ os,
                                                    float* __restrict__ out) {
  __shared__ float Dst[3][DD*LDSTm];       // 3-buffer rotation (9.3 KB)
  const int gid = blockIdx.x;
  const int b = gid & 7;                   // XCD affinity (matches prep)
  int t = gid >> 3;
  const int mt = t % 3; t /= 3;
  const int m0 = mt << 4;
  const int g = t & 31;                    // y-pair id
  const int i0 = (t >> 5) * NI;
  const int y0 = (g >> 1)*4 + (g & 1);     // pairs {y0,y0+2} cover all 64 y
  const int p = threadIdx.x >> 6;
  const int lane = threadIdx.x & 63;
  const int lr = lane & 15, lg = lane >> 4;
  const float scale = s1[0]*s2[0] / (96.0f * os[0]);

  // A fragments for both y's of the pair (named arrays; rule #20)
  sh8 aF0[3], aF1[3];
  {
    const unsigned short* a0 =
        g_d1F + (size_t)((b*H_ + y0)*2 + p)*(9*512) + (size_t)mt*3*512 + lane*8;
    const unsigned short* a1 =
        g_d1F + (size_t)((b*H_ + y0 + 2)*2 + p)*(9*512) + (size_t)mt*3*512 + lane*8;
    #pragma unroll
    for (int k = 0; k < 3; ++k) {
      aF0[k] = *(const sh8*)(a0 + k*512);
      aF1[k] = *(const sh8*)(a1 + k*512);
    }
  }

  sh8 bF[9];
  const int r0 = y0 + 2*i0;                // B row for (y0, i0)
  LOADB(bF, r0);                           // combo 0
  COMBO(aF0, y0, i0, 0);
  #pragma unroll
  for (int d = 1; d < NI; ++d) {           // combos 2d-1, 2d
    LOADB(bF, r0 + 2*d);
    COMBO(aF0, y0,     i0 + d,     (2*d - 1) % 3);
    COMBO(aF1, y0 + 2, i0 + d - 1, (2*d) % 3);
  }
  LOADB(bF, r0 + 2*NI);                    // combo 13
  COMBO(aF1, y0 + 2, i0 + NI - 1, (2*NI - 1) % 3);
}

extern "C" void kernel_launch(void* const* d_in, const int* in_sizes, int n_in,
                              void* d_out, int out_size, void* d_ws, size_t ws_size,
                              hipStream_t stream) {
  const float* d1 = (const float*)d_in[0];
  const float* d2 = (const float*)d_in[1];
  const float* s1 = (const float*)d_in[2];
  const float* s2 = (const float*)d_in[3];
  const float* os = (const float*)d_in[5];   // inter_scale (d_in[4]) unused

  prep_all<<<128*B_, 256, 0, stream>>>(d1, d2);
  corr_main<<<B_*3*32*ISPLIT, 128, 0, stream>>>(s1, s2, os, (float*)d_out);
}